// Round 12
// baseline (162.130 us; speedup 1.0000x reference)
//
#include <hip/hip_runtime.h>
#include <stdint.h>

#define NN 100000     // nodes
#define NE 640000     // edges
#define DD 128        // features
#define BN_EPS 1e-5f
#define NB 391        // scan blocks: 391*256 = 100096 >= NN
#define NROWPAD 100096
#define NTILE 782     // 128-row tiles: 782*128 = 100096
#define GGRID 512     // gemm grid (2 blocks/CU)

// merged setup-kernel block ranges
#define SETUP_PREPX_BLOCKS 6256   // NROWPAD*16/256
#define SETUP_PREPW_BLOCKS 128
#define SETUP_HIST_BLOCKS  2500

typedef __attribute__((ext_vector_type(8)))  short bf16x8;
typedef __attribute__((ext_vector_type(4)))  float f32x4;

static __device__ __forceinline__ float bf2f(unsigned short s) {
  return __uint_as_float(((unsigned)s) << 16);
}
static __device__ __forceinline__ unsigned short f2bf(float f) {
  unsigned u = __float_as_uint(f);
  u += 0x7FFFu + ((u >> 16) & 1u);   // RNE
  return (unsigned short)(u >> 16);
}

// ---- 0. zero deg ---------------------------------------------------------
__global__ __launch_bounds__(1024) void k_zero(int* __restrict__ deg)
{
  int i = blockIdx.x * 1024 + threadIdx.x;
  if (i < NROWPAD) deg[i] = 0;
}

// ---- 1. merged setup: prepx (incl. pad-row zero) + prepw + hist ----------
__global__ __launch_bounds__(256) void k_setup(
    const float* __restrict__ x,
    const float* __restrict__ Wl, const float* __restrict__ Wr,
    const int* __restrict__ ei,
    unsigned short* __restrict__ abuf, unsigned short* __restrict__ wbf,
    int* __restrict__ deg)
{
  int b = blockIdx.x;
  if (b < SETUP_PREPX_BLOCKS) {
    // abuf[row][128+j] = bf16(relu(x[row][j])); pad rows zero BOTH halves
    int i = b * 256 + threadIdx.x;      // 0 .. NROWPAD*16-1
    int row = i >> 4, cj = i & 15;
    if (row < NN) {
      const float* xp = x + (long)row * DD + cj * 8;
      float tmp[8];
      *(float4*)(tmp)     = *(const float4*)(xp);
      *(float4*)(tmp + 4) = *(const float4*)(xp + 4);
      bf16x8 o;
#pragma unroll
      for (int e = 0; e < 8; ++e) o[e] = (short)f2bf(fmaxf(tmp[e], 0.f));
      *(bf16x8*)(abuf + (long)row * 256 + DD + cj * 8) = o;
    } else {                            // rows NN..NROWPAD-1: zero fill
      bf16x8 z = {};
      *(bf16x8*)(abuf + (long)row * 256 + cj * 8) = z;        // agg half
      *(bf16x8*)(abuf + (long)row * 256 + DD + cj * 8) = z;   // x half
    }
  } else if (b < SETUP_PREPX_BLOCKS + SETUP_PREPW_BLOCKS) {
    // wbf[col][0..255] = [Wl[col][:] | Wr[col][:]] as bf16
    int i = (b - SETUP_PREPX_BLOCKS) * 256 + threadIdx.x;
    int col = i >> 8, k = i & 255;
    float v = (k < DD) ? Wl[col * DD + k] : Wr[col * DD + (k - DD)];
    wbf[i] = f2bf(v);
  } else {
    // degree histogram
    int e = (b - SETUP_PREPX_BLOCKS - SETUP_PREPW_BLOCKS) * 256 + threadIdx.x;
    if (e < NE) atomicAdd(deg + ei[NE + e], 1);
  }
}

// ---- 4. block sums -------------------------------------------------------
__global__ __launch_bounds__(256) void k_scan1(const int* __restrict__ deg,
                                               int* __restrict__ bsum)
{
  __shared__ int sc[256];
  int t = threadIdx.x;
  sc[t] = deg[blockIdx.x * 256 + t];
  __syncthreads();
  for (int s = 128; s > 0; s >>= 1) {
    if (t < s) sc[t] += sc[t + s];
    __syncthreads();
  }
  if (t == 0) bsum[blockIdx.x] = sc[0];
}

// ---- 5. exclusive scan of block sums ------------------------------------
__global__ __launch_bounds__(512) void k_scan2(const int* __restrict__ bsum,
                                               int* __restrict__ boff)
{
  __shared__ int sc[512];
  int t = threadIdx.x;
  int v = (t < NB) ? bsum[t] : 0;
  sc[t] = v;
  __syncthreads();
  for (int s = 1; s < 512; s <<= 1) {
    int add = (t >= s) ? sc[t - s] : 0;
    __syncthreads();
    sc[t] += add;
    __syncthreads();
  }
  if (t < NB) boff[t] = sc[t] - v;
}

// ---- 6. per-element exclusive scan -> offs; deg becomes fill-cursor ------
__global__ __launch_bounds__(256) void k_scan3(int* __restrict__ deg,
                                               const int* __restrict__ boff,
                                               int* __restrict__ offs)
{
  __shared__ int sc[256];
  int t = threadIdx.x;
  int i = blockIdx.x * 256 + t;
  int v = deg[i];
  sc[t] = v;
  __syncthreads();
  for (int s = 1; s < 256; s <<= 1) {
    int add = (t >= s) ? sc[t - s] : 0;
    __syncthreads();
    sc[t] += add;
    __syncthreads();
  }
  int excl = sc[t] - v + boff[blockIdx.x];
  offs[i] = excl;
  deg[i]  = excl;
}

// ---- 7. fill CSR ---------------------------------------------------------
__global__ __launch_bounds__(256) void k_fill(const int* __restrict__ ei,
                                              int* __restrict__ cursor,
                                              int* __restrict__ esrc)
{
  int e = blockIdx.x * 256 + threadIdx.x;
  if (e >= NE) return;
  int pos = atomicAdd(cursor + ei[NE + e], 1);
  esrc[pos] = ei[e];
}

// ---- 8. gather-aggregate: abuf[dst][0..127] = bf16(mean(relu_x_bf16[src]))
// R7/R10-proven 4x16 layout: 4 quarter-waves of 16 lanes own edge stream
// i*4+q; each lane reads bf16x8 (16B) -> one wave-wide load covers 4
// DIFFERENT edges' rows (4x MLP; 8x with unroll 2). R9's 8x8 variant went
// VALU-bound on the tripled reduce tail -- do not repeat. Lanes past the
// edge count hold src=NN (zeroed pad row) -> adds 0, branch-free.
__global__ __launch_bounds__(256) void k_agg(const int* __restrict__ offs,
                                             const int* __restrict__ esrc,
                                             unsigned short* __restrict__ abuf)
{
  int dst = blockIdx.x * 4 + (threadIdx.x >> 6);
  if (dst >= NN) return;
  int lane = threadIdx.x & 63;
  int q  = lane >> 4;        // quarter-wave 0..3 = edge slot
  int fl = lane & 15;        // feature lane: feats fl*8 .. fl*8+7
  int off = offs[dst], end = offs[dst + 1];
  int deg = end - off;
  float acc[8];
#pragma unroll
  for (int e = 0; e < 8; ++e) acc[e] = 0.f;

  for (int base = off; base < end; base += 64) {
    int m = end - base; if (m > 64) m = 64;
    int mysrc = (base + lane < end) ? esrc[base + lane] : NN;  // NN = zero pad row
    int iters = (m + 3) >> 2;
#pragma unroll 2
    for (int i = 0; i < iters; ++i) {
      int src = __shfl(mysrc, i * 4 + q);    // i*4+q <= 63; >=m lanes hold NN
      bf16x8 w = *(const bf16x8*)(abuf + (long)src * 256 + DD + fl * 8);
#pragma unroll
      for (int e = 0; e < 8; ++e) acc[e] += bf2f((unsigned short)w[e]);
    }
  }

#pragma unroll
  for (int e = 0; e < 8; ++e) {
    acc[e] += __shfl_xor(acc[e], 16);
    acc[e] += __shfl_xor(acc[e], 32);
  }
  if (q == 0) {
    float rinv = (deg > 0) ? 1.0f / (float)deg : 0.f;
    bf16x8 o;
#pragma unroll
    for (int e = 0; e < 8; ++e) o[e] = (short)f2bf(acc[e] * rinv);
    *(bf16x8*)(abuf + (long)dst * 256 + fl * 8) = o;
  }
}

// ======== streaming GEMM (single pass now) ================================
// Block: 512 thr = 8 waves. B (= wbf, 128x256 bf16 = 64KB) staged once in
// LDS with XOR-swizzle byte ^= (col&7)<<4. Each wave owns a 16-row strip
// per tile; A-fragments load DIRECTLY from global. No barriers in loop.
// REGISTER BUDGET: (512,2) caps VGPR at 128 (2 blocks/CU, LDS-bound).
// R11: gemm2 recompute ELIMINATED. gemm1 stores out_pre as bf16 into
// abuf's agg-half (dead after this kernel; each wave writes only rows it
// alone reads, after its tile compute -> no hazard). k_norm streams the
// BN affine at HBM rate. Bias stays folded into k_stats' shift.
#define GEMM_STAGE_B() \
  _Pragma("unroll") \
  for (int j = 0; j < 8; ++j) { \
    int id = j * 512 + t, col = id >> 5, seg = id & 31; \
    uint4 v = *(const uint4*)(wbf + col * 256 + seg * 8); \
    int byte = (col << 9) + (seg << 4); byte ^= (col & 7) << 4; \
    *(uint4*)((char*)blds + byte) = v; \
  } \
  __syncthreads();

#define GEMM_TILE_COMPUTE(rb) \
  { const unsigned short* ap = abuf + (long)((rb) + c15) * 256 + kg * 8; \
    _Pragma("unroll 4") \
    for (int ks = 0; ks < 8; ++ks) { \
      bf16x8 a = *(const bf16x8*)(ap + ks * 32); \
      _Pragma("unroll") \
      for (int ct = 0; ct < 8; ++ct) { \
        int byte = ((ct * 16 + c15) << 9) + (ks << 6) + (kg << 4); \
        byte ^= (c15 & 7) << 4; \
        bf16x8 b = *(const bf16x8*)((const char*)blds + byte); \
        acc[ct] = __builtin_amdgcn_mfma_f32_16x16x32_bf16(a, b, acc[ct], 0, 0, 0); \
      } \
    } }

// ---- 9a. GEMM: raw column stats + bf16 out_pre into abuf agg-half --------
// Pad rows are zeroed in abuf -> A rows zero -> acc 0 -> contribute 0 to
// stats and store 0s (harmless).
__global__ __launch_bounds__(512, 2) void k_gemm1(
    unsigned short* __restrict__ abuf,
    const unsigned short* __restrict__ wbf,
    float* __restrict__ partials)
{
  __shared__ __align__(16) unsigned short blds[32768];   // 64KB B
  const int t = threadIdx.x;
  const int lane = t & 63, wv = t >> 6;
  const int c15 = lane & 15, kg = lane >> 4;

  GEMM_STAGE_B();

  float sS[8], sQ[8];
#pragma unroll
  for (int ct = 0; ct < 8; ++ct) { sS[ct] = 0.f; sQ[ct] = 0.f; }

  for (int tile = blockIdx.x; tile < NTILE; tile += GGRID) {
    int rb = tile * 128 + wv * 16;
    f32x4 acc[8];
#pragma unroll
    for (int ct = 0; ct < 8; ++ct) acc[ct] = (f32x4){0.f, 0.f, 0.f, 0.f};
    GEMM_TILE_COMPUTE(rb);
#pragma unroll
    for (int ct = 0; ct < 8; ++ct) {
      int col = ct * 16 + c15;
#pragma unroll
      for (int r = 0; r < 4; ++r) {
        float v = acc[ct][r];
        sS[ct] += v;
        sQ[ct] += v * v;
        abuf[(long)(rb + kg * 4 + r) * 256 + col] = f2bf(v);  // out_pre bf16
      }
    }
  }

  // block-level reduce through LDS (B no longer needed)
  __syncthreads();
  float* slds = (float*)blds;   // [8 waves][256] = 8KB
#pragma unroll
  for (int ct = 0; ct < 8; ++ct) {
    float s = sS[ct], q = sQ[ct];
    s += __shfl_xor(s, 16); q += __shfl_xor(q, 16);
    s += __shfl_xor(s, 32); q += __shfl_xor(q, 32);
    if (lane < 16) {
      slds[wv * 256 + ct * 16 + lane] = s;
      slds[wv * 256 + 128 + ct * 16 + lane] = q;
    }
  }
  __syncthreads();
  if (t < 256) {
    float a = 0.f;
#pragma unroll
    for (int w = 0; w < 8; ++w) a += slds[w * 256 + t];
    partials[blockIdx.x * 256 + t] = a;
  }
}

// ---- 9b. reduce partials; fold bias; emit sc / (bias*sc + shift) ---------
__global__ __launch_bounds__(1024) void k_stats(
    const float* __restrict__ partials, const float* __restrict__ bl,
    const float* __restrict__ gamma, const float* __restrict__ beta,
    float* __restrict__ ss)
{
  __shared__ float red[4][256];
  int t = threadIdx.x & 255, g = threadIdx.x >> 8;
  float a = 0.f;
#pragma unroll 8
  for (int blk = g; blk < GGRID; blk += 4) a += partials[blk * 256 + t];
  red[g][t] = a;
  __syncthreads();
  if (threadIdx.x < 256)
    red[0][t] = red[0][t] + red[1][t] + red[2][t] + red[3][t];
  __syncthreads();
  if (threadIdx.x < 128) {
    float Sr = red[0][t], Qr = red[0][128 + t];
    float b  = bl[t];
    float S  = Sr + (float)NN * b;                    // fold bias into stats
    float Q  = Qr + 2.f * b * Sr + (float)NN * b * b;
    float mu  = S / (float)NN;
    float var = Q / (float)NN - mu * mu;              // biased variance
    float rsig = rsqrtf(var + BN_EPS);
    float sc  = gamma[t] * rsig;
    float sh2 = beta[t] - mu * sc;
    ss[t]       = sc;
    ss[128 + t] = b * sc + sh2;                       // bias folded into shift
  }
}

// ---- 9c. streaming BN affine: out = sc * out_pre(bf16) + shift -----------
// Reads 25.6MB bf16, writes 51.2MB f32 -- pure streaming, no recompute.
__global__ __launch_bounds__(256) void k_norm(
    const unsigned short* __restrict__ abuf,
    const float* __restrict__ ss,
    float* __restrict__ out)
{
  __shared__ float sc[128], sh[128];
  if (threadIdx.x < 128) {
    sc[threadIdx.x] = ss[threadIdx.x];
    sh[threadIdx.x] = ss[128 + threadIdx.x];
  }
  __syncthreads();
  int i = blockIdx.x * 256 + threadIdx.x;   // 0 .. NN*16-1
  int row = i >> 4, cj = i & 15;
  if (row >= NN) return;
  bf16x8 v = *(const bf16x8*)(abuf + (long)row * 256 + cj * 8);
  int c0 = cj * 8;
  float4 o0, o1;
  o0.x = fmaf(bf2f((unsigned short)v[0]), sc[c0 + 0], sh[c0 + 0]);
  o0.y = fmaf(bf2f((unsigned short)v[1]), sc[c0 + 1], sh[c0 + 1]);
  o0.z = fmaf(bf2f((unsigned short)v[2]), sc[c0 + 2], sh[c0 + 2]);
  o0.w = fmaf(bf2f((unsigned short)v[3]), sc[c0 + 3], sh[c0 + 3]);
  o1.x = fmaf(bf2f((unsigned short)v[4]), sc[c0 + 4], sh[c0 + 4]);
  o1.y = fmaf(bf2f((unsigned short)v[5]), sc[c0 + 5], sh[c0 + 5]);
  o1.z = fmaf(bf2f((unsigned short)v[6]), sc[c0 + 6], sh[c0 + 6]);
  o1.w = fmaf(bf2f((unsigned short)v[7]), sc[c0 + 7], sh[c0 + 7]);
  *(float4*)(out + (long)row * DD + c0)     = o0;
  *(float4*)(out + (long)row * DD + c0 + 4) = o1;
}

extern "C" void kernel_launch(void* const* d_in, const int* in_sizes, int n_in,
                              void* d_out, int out_size, void* d_ws, size_t ws_size,
                              hipStream_t stream)
{
  const float* x     = (const float*)d_in[0];
  // d_in[1] = edge_attr — unused by the reference
  const float* Wl    = (const float*)d_in[2];
  const float* bl    = (const float*)d_in[3];
  const float* Wr    = (const float*)d_in[4];
  const float* gamma = (const float*)d_in[5];
  const float* beta  = (const float*)d_in[6];
  const int*   ei    = (const int*)d_in[7];
  float* out = (float*)d_out;

  char* ws = (char*)d_ws;
  unsigned short* abuf = (unsigned short*)(ws);            // 100096*256*2 = 51,249,152
  int*   esrc  = (int*)(ws + 51249152);                    //  2,560,000 -> 53,809,152
  int*   deg   = (int*)(ws + 53809152);                    //    400,384 -> 54,209,536
  int*   offs  = (int*)(ws + 54209536);                    //    400,384 -> 54,609,920
  int*   bsum  = (int*)(ws + 54609920);                    //      2,048 -> 54,611,968
  int*   boff  = (int*)(ws + 54611968);                    //      2,048 -> 54,614,016
  unsigned short* wbf = (unsigned short*)(ws + 54614016);  //     65,536 -> 54,679,552
  // dead-region reuse (stream-ordered):
  float* partials = (float*)esrc;   // gemm1 partials [512][256] f32; esrc dead after k_agg
  float* ssbuf    = (float*)deg;    // 256 f32; deg dead after k_fill
  (void)ws_size; (void)in_sizes; (void)n_in; (void)out_size;

  k_zero  <<<98,   1024, 0, stream>>>(deg);
  k_setup <<<SETUP_PREPX_BLOCKS + SETUP_PREPW_BLOCKS + SETUP_HIST_BLOCKS,
             256, 0, stream>>>(x, Wl, Wr, ei, abuf, wbf, deg);
  k_scan1 <<<NB,    256, 0, stream>>>(deg, bsum);
  k_scan2 <<<1,     512, 0, stream>>>(bsum, boff);
  k_scan3 <<<NB,    256, 0, stream>>>(deg, boff, offs);
  k_fill  <<<2500,  256, 0, stream>>>(ei, deg, esrc);
  k_agg   <<<25000, 256, 0, stream>>>(offs, esrc, abuf);
  k_gemm1 <<<GGRID, 512, 0, stream>>>(abuf, wbf, partials);
  k_stats <<<1,    1024, 0, stream>>>(partials, bl, gamma, beta, ssbuf);
  k_norm  <<<6250,  256, 0, stream>>>(abuf, ssbuf, out);
}

// Round 13
// 154.473 us; speedup vs baseline: 1.0496x; 1.0496x over previous
//
#include <hip/hip_runtime.h>
#include <stdint.h>

#define NN 100000     // nodes
#define NE 640000     // edges
#define DD 128        // features
#define BN_EPS 1e-5f
#define NB 391        // scan blocks: 391*256 = 100096 >= NN
#define NROWPAD 100096
#define NTILE 782     // 128-row tiles: 782*128 = 100096
#define GGRID 512     // gemm grid (2 blocks/CU)

typedef __attribute__((ext_vector_type(8)))  short bf16x8;
typedef __attribute__((ext_vector_type(4)))  float f32x4;

static __device__ __forceinline__ float bf2f(unsigned short s) {
  return __uint_as_float(((unsigned)s) << 16);
}
static __device__ __forceinline__ unsigned short f2bf(float f) {
  unsigned u = __float_as_uint(f);
  u += 0x7FFFu + ((u >> 16) & 1u);   // RNE
  return (unsigned short)(u >> 16);
}

// ---- 0. zero deg ---------------------------------------------------------
__global__ __launch_bounds__(1024) void k_zero(int* __restrict__ deg)
{
  int i = blockIdx.x * 1024 + threadIdx.x;
  if (i < NROWPAD) deg[i] = 0;
}

// ---- 1. merged setup, INTERLEAVED roles ----------------------------------
// R12: hist blocks (640K device-scope atomics, ~25us) previously dispatched
// AFTER all prep blocks -> phases ran sequentially. Now every 4th block is
// hist (b&3==3 -> exactly 2500), spread uniformly so atomics overlap the
// prep streaming from t=0. Non-hist rank = b - b/4: 0..6255 prepx,
// 6256..6383 prepw, rest idle.
__global__ __launch_bounds__(256) void k_setup(
    const float* __restrict__ x,
    const float* __restrict__ Wl, const float* __restrict__ Wr,
    const int* __restrict__ ei,
    unsigned short* __restrict__ abuf, unsigned short* __restrict__ wbf,
    int* __restrict__ deg)
{
  int b = blockIdx.x;                   // grid 10000
  if ((b & 3) == 3) {
    // degree histogram (2500 blocks, uniformly spread in dispatch order)
    int e = (b >> 2) * 256 + threadIdx.x;
    if (e < NE) atomicAdd(deg + ei[NE + e], 1);
    return;
  }
  int rank = b - (b >> 2);              // 0..7499
  if (rank < 6256) {
    // abuf[row][128+j] = bf16(relu(x[row][j])); pad rows zero BOTH halves
    int i = rank * 256 + threadIdx.x;   // 0 .. NROWPAD*16-1
    int row = i >> 4, cj = i & 15;
    if (row < NN) {
      const float* xp = x + (long)row * DD + cj * 8;
      float tmp[8];
      *(float4*)(tmp)     = *(const float4*)(xp);
      *(float4*)(tmp + 4) = *(const float4*)(xp + 4);
      bf16x8 o;
#pragma unroll
      for (int e = 0; e < 8; ++e) o[e] = (short)f2bf(fmaxf(tmp[e], 0.f));
      *(bf16x8*)(abuf + (long)row * 256 + DD + cj * 8) = o;
    } else {                            // rows NN..NROWPAD-1: zero fill
      bf16x8 z = {};
      *(bf16x8*)(abuf + (long)row * 256 + cj * 8) = z;        // agg half
      *(bf16x8*)(abuf + (long)row * 256 + DD + cj * 8) = z;   // x half
    }
  } else if (rank < 6384) {
    // wbf[col][0..255] = [Wl[col][:] | Wr[col][:]] as bf16
    int i = (rank - 6256) * 256 + threadIdx.x;
    int col = i >> 8, k = i & 255;
    float v = (k < DD) ? Wl[col * DD + k] : Wr[col * DD + (k - DD)];
    wbf[i] = f2bf(v);
  }
}

// ---- 4. block sums -------------------------------------------------------
__global__ __launch_bounds__(256) void k_scan1(const int* __restrict__ deg,
                                               int* __restrict__ bsum)
{
  __shared__ int sc[256];
  int t = threadIdx.x;
  sc[t] = deg[blockIdx.x * 256 + t];
  __syncthreads();
  for (int s = 128; s > 0; s >>= 1) {
    if (t < s) sc[t] += sc[t + s];
    __syncthreads();
  }
  if (t == 0) bsum[blockIdx.x] = sc[0];
}

// ---- 6. per-element exclusive scan (self-computes block prefix) ----------
// R12: k_scan2 eliminated. Each block reduces bsum[0..blockIdx-1] itself
// (<=391 ints, 2 strided loads + LDS reduce) -- one fewer graph node.
__global__ __launch_bounds__(256) void k_scan3(int* __restrict__ deg,
                                               const int* __restrict__ bsum,
                                               int* __restrict__ offs)
{
  __shared__ int sc[256];
  __shared__ int pre[256];
  int t = threadIdx.x;
  // block prefix: sum of bsum[j] for j < blockIdx.x
  int p = 0;
  for (int j = t; j < blockIdx.x; j += 256) p += bsum[j];
  pre[t] = p;
  __syncthreads();
  for (int s = 128; s > 0; s >>= 1) {
    if (t < s) pre[t] += pre[t + s];
    __syncthreads();
  }
  int boff = pre[0];
  __syncthreads();
  // intra-block exclusive scan of deg
  int i = blockIdx.x * 256 + t;
  int v = deg[i];
  sc[t] = v;
  __syncthreads();
  for (int s = 1; s < 256; s <<= 1) {
    int add = (t >= s) ? sc[t - s] : 0;
    __syncthreads();
    sc[t] += add;
    __syncthreads();
  }
  int excl = sc[t] - v + boff;
  offs[i] = excl;
  deg[i]  = excl;     // deg becomes fill-cursor
}

// ---- 7. fill CSR ---------------------------------------------------------
__global__ __launch_bounds__(256) void k_fill(const int* __restrict__ ei,
                                              int* __restrict__ cursor,
                                              int* __restrict__ esrc)
{
  int e = blockIdx.x * 256 + threadIdx.x;
  if (e >= NE) return;
  int pos = atomicAdd(cursor + ei[NE + e], 1);
  esrc[pos] = ei[e];
}

// ---- 8. gather-aggregate: abuf[dst][0..127] = bf16(mean(relu_x_bf16[src]))
// R7/R10-proven 4x16 layout: 4 quarter-waves of 16 lanes own edge stream
// i*4+q; each lane reads bf16x8 (16B) -> one wave-wide load covers 4
// DIFFERENT edges' rows (4x MLP; 8x with unroll 2). R9's 8x8 variant went
// VALU-bound on the tripled reduce tail -- do not repeat. Lanes past the
// edge count hold src=NN (zeroed pad row) -> adds 0, branch-free.
__global__ __launch_bounds__(256) void k_agg(const int* __restrict__ offs,
                                             const int* __restrict__ esrc,
                                             unsigned short* __restrict__ abuf)
{
  int dst = blockIdx.x * 4 + (threadIdx.x >> 6);
  if (dst >= NN) return;
  int lane = threadIdx.x & 63;
  int q  = lane >> 4;        // quarter-wave 0..3 = edge slot
  int fl = lane & 15;        // feature lane: feats fl*8 .. fl*8+7
  int off = offs[dst], end = offs[dst + 1];
  int deg = end - off;
  float acc[8];
#pragma unroll
  for (int e = 0; e < 8; ++e) acc[e] = 0.f;

  for (int base = off; base < end; base += 64) {
    int m = end - base; if (m > 64) m = 64;
    int mysrc = (base + lane < end) ? esrc[base + lane] : NN;  // NN = zero pad row
    int iters = (m + 3) >> 2;
#pragma unroll 2
    for (int i = 0; i < iters; ++i) {
      int src = __shfl(mysrc, i * 4 + q);    // i*4+q <= 63; >=m lanes hold NN
      bf16x8 w = *(const bf16x8*)(abuf + (long)src * 256 + DD + fl * 8);
#pragma unroll
      for (int e = 0; e < 8; ++e) acc[e] += bf2f((unsigned short)w[e]);
    }
  }

#pragma unroll
  for (int e = 0; e < 8; ++e) {
    acc[e] += __shfl_xor(acc[e], 16);
    acc[e] += __shfl_xor(acc[e], 32);
  }
  if (q == 0) {
    float rinv = (deg > 0) ? 1.0f / (float)deg : 0.f;
    bf16x8 o;
#pragma unroll
    for (int e = 0; e < 8; ++e) o[e] = (short)f2bf(acc[e] * rinv);
    *(bf16x8*)(abuf + (long)dst * 256 + fl * 8) = o;
  }
}

// ======== streaming GEMM (single pass) ====================================
// Block: 512 thr = 8 waves. B (= wbf, 128x256 bf16 = 64KB) staged once in
// LDS with XOR-swizzle byte ^= (col&7)<<4. Each wave owns a 16-row strip
// per tile; A-fragments load DIRECTLY from global. No barriers in loop.
// REGISTER BUDGET: (512,2) caps VGPR at 128 (2 blocks/CU, LDS-bound).
// A-load unroll 4. gemm stores out_pre bf16 into abuf agg-half (dead after
// this kernel; each wave touches only rows it alone reads). Bias folded
// into k_stats' shift.
#define GEMM_STAGE_B() \
  _Pragma("unroll") \
  for (int j = 0; j < 8; ++j) { \
    int id = j * 512 + t, col = id >> 5, seg = id & 31; \
    uint4 v = *(const uint4*)(wbf + col * 256 + seg * 8); \
    int byte = (col << 9) + (seg << 4); byte ^= (col & 7) << 4; \
    *(uint4*)((char*)blds + byte) = v; \
  } \
  __syncthreads();

#define GEMM_TILE_COMPUTE(rb) \
  { const unsigned short* ap = abuf + (long)((rb) + c15) * 256 + kg * 8; \
    _Pragma("unroll 4") \
    for (int ks = 0; ks < 8; ++ks) { \
      bf16x8 a = *(const bf16x8*)(ap + ks * 32); \
      _Pragma("unroll") \
      for (int ct = 0; ct < 8; ++ct) { \
        int byte = ((ct * 16 + c15) << 9) + (ks << 6) + (kg << 4); \
        byte ^= (c15 & 7) << 4; \
        bf16x8 b = *(const bf16x8*)((const char*)blds + byte); \
        acc[ct] = __builtin_amdgcn_mfma_f32_16x16x32_bf16(a, b, acc[ct], 0, 0, 0); \
      } \
    } }

// ---- 9a. GEMM: raw column stats + bf16 out_pre into abuf agg-half --------
__global__ __launch_bounds__(512, 2) void k_gemm1(
    unsigned short* __restrict__ abuf,
    const unsigned short* __restrict__ wbf,
    float* __restrict__ partials)
{
  __shared__ __align__(16) unsigned short blds[32768];   // 64KB B
  const int t = threadIdx.x;
  const int lane = t & 63, wv = t >> 6;
  const int c15 = lane & 15, kg = lane >> 4;

  GEMM_STAGE_B();

  float sS[8], sQ[8];
#pragma unroll
  for (int ct = 0; ct < 8; ++ct) { sS[ct] = 0.f; sQ[ct] = 0.f; }

  for (int tile = blockIdx.x; tile < NTILE; tile += GGRID) {
    int rb = tile * 128 + wv * 16;
    f32x4 acc[8];
#pragma unroll
    for (int ct = 0; ct < 8; ++ct) acc[ct] = (f32x4){0.f, 0.f, 0.f, 0.f};
    GEMM_TILE_COMPUTE(rb);
#pragma unroll
    for (int ct = 0; ct < 8; ++ct) {
      int col = ct * 16 + c15;
#pragma unroll
      for (int r = 0; r < 4; ++r) {
        float v = acc[ct][r];
        sS[ct] += v;
        sQ[ct] += v * v;
        abuf[(long)(rb + kg * 4 + r) * 256 + col] = f2bf(v);  // out_pre bf16
      }
    }
  }

  // block-level reduce through LDS (B no longer needed)
  __syncthreads();
  float* slds = (float*)blds;   // [8 waves][256] = 8KB
#pragma unroll
  for (int ct = 0; ct < 8; ++ct) {
    float s = sS[ct], q = sQ[ct];
    s += __shfl_xor(s, 16); q += __shfl_xor(q, 16);
    s += __shfl_xor(s, 32); q += __shfl_xor(q, 32);
    if (lane < 16) {
      slds[wv * 256 + ct * 16 + lane] = s;
      slds[wv * 256 + 128 + ct * 16 + lane] = q;
    }
  }
  __syncthreads();
  if (t < 256) {
    float a = 0.f;
#pragma unroll
    for (int w = 0; w < 8; ++w) a += slds[w * 256 + t];
    partials[blockIdx.x * 256 + t] = a;
  }
}

// ---- 9b. reduce partials; fold bias; emit sc / (bias*sc + shift) ---------
__global__ __launch_bounds__(1024) void k_stats(
    const float* __restrict__ partials, const float* __restrict__ bl,
    const float* __restrict__ gamma, const float* __restrict__ beta,
    float* __restrict__ ss)
{
  __shared__ float red[4][256];
  int t = threadIdx.x & 255, g = threadIdx.x >> 8;
  float a = 0.f;
#pragma unroll 8
  for (int blk = g; blk < GGRID; blk += 4) a += partials[blk * 256 + t];
  red[g][t] = a;
  __syncthreads();
  if (threadIdx.x < 256)
    red[0][t] = red[0][t] + red[1][t] + red[2][t] + red[3][t];
  __syncthreads();
  if (threadIdx.x < 128) {
    float Sr = red[0][t], Qr = red[0][128 + t];
    float b  = bl[t];
    float S  = Sr + (float)NN * b;                    // fold bias into stats
    float Q  = Qr + 2.f * b * Sr + (float)NN * b * b;
    float mu  = S / (float)NN;
    float var = Q / (float)NN - mu * mu;              // biased variance
    float rsig = rsqrtf(var + BN_EPS);
    float sc  = gamma[t] * rsig;
    float sh2 = beta[t] - mu * sc;
    ss[t]       = sc;
    ss[128 + t] = b * sc + sh2;                       // bias folded into shift
  }
}

// ---- 9c. streaming BN affine: out = sc * out_pre(bf16) + shift -----------
__global__ __launch_bounds__(256) void k_norm(
    const unsigned short* __restrict__ abuf,
    const float* __restrict__ ss,
    float* __restrict__ out)
{
  __shared__ float sc[128], sh[128];
  if (threadIdx.x < 128) {
    sc[threadIdx.x] = ss[threadIdx.x];
    sh[threadIdx.x] = ss[128 + threadIdx.x];
  }
  __syncthreads();
  int i = blockIdx.x * 256 + threadIdx.x;   // 0 .. NN*16-1
  int row = i >> 4, cj = i & 15;
  if (row >= NN) return;
  bf16x8 v = *(const bf16x8*)(abuf + (long)row * 256 + cj * 8);
  int c0 = cj * 8;
  float4 o0, o1;
  o0.x = fmaf(bf2f((unsigned short)v[0]), sc[c0 + 0], sh[c0 + 0]);
  o0.y = fmaf(bf2f((unsigned short)v[1]), sc[c0 + 1], sh[c0 + 1]);
  o0.z = fmaf(bf2f((unsigned short)v[2]), sc[c0 + 2], sh[c0 + 2]);
  o0.w = fmaf(bf2f((unsigned short)v[3]), sc[c0 + 3], sh[c0 + 3]);
  o1.x = fmaf(bf2f((unsigned short)v[4]), sc[c0 + 4], sh[c0 + 4]);
  o1.y = fmaf(bf2f((unsigned short)v[5]), sc[c0 + 5], sh[c0 + 5]);
  o1.z = fmaf(bf2f((unsigned short)v[6]), sc[c0 + 6], sh[c0 + 6]);
  o1.w = fmaf(bf2f((unsigned short)v[7]), sc[c0 + 7], sh[c0 + 7]);
  *(float4*)(out + (long)row * DD + c0)     = o0;
  *(float4*)(out + (long)row * DD + c0 + 4) = o1;
}

extern "C" void kernel_launch(void* const* d_in, const int* in_sizes, int n_in,
                              void* d_out, int out_size, void* d_ws, size_t ws_size,
                              hipStream_t stream)
{
  const float* x     = (const float*)d_in[0];
  // d_in[1] = edge_attr — unused by the reference
  const float* Wl    = (const float*)d_in[2];
  const float* bl    = (const float*)d_in[3];
  const float* Wr    = (const float*)d_in[4];
  const float* gamma = (const float*)d_in[5];
  const float* beta  = (const float*)d_in[6];
  const int*   ei    = (const int*)d_in[7];
  float* out = (float*)d_out;

  char* ws = (char*)d_ws;
  unsigned short* abuf = (unsigned short*)(ws);            // 100096*256*2 = 51,249,152
  int*   esrc  = (int*)(ws + 51249152);                    //  2,560,000 -> 53,809,152
  int*   deg   = (int*)(ws + 53809152);                    //    400,384 -> 54,209,536
  int*   offs  = (int*)(ws + 54209536);                    //    400,384 -> 54,609,920
  int*   bsum  = (int*)(ws + 54609920);                    //      2,048 -> 54,611,968
  unsigned short* wbf = (unsigned short*)(ws + 54611968);  //     65,536 -> 54,677,504
  // dead-region reuse (stream-ordered):
  float* partials = (float*)esrc;   // gemm1 partials [512][256] f32; esrc dead after k_agg
  float* ssbuf    = (float*)deg;    // 256 f32; deg dead after k_fill
  (void)ws_size; (void)in_sizes; (void)n_in; (void)out_size;

  k_zero  <<<98,   1024, 0, stream>>>(deg);
  k_setup <<<10000, 256, 0, stream>>>(x, Wl, Wr, ei, abuf, wbf, deg);
  k_scan1 <<<NB,    256, 0, stream>>>(deg, bsum);
  k_scan3 <<<NB,    256, 0, stream>>>(deg, bsum, offs);
  k_fill  <<<2500,  256, 0, stream>>>(ei, deg, esrc);
  k_agg   <<<25000, 256, 0, stream>>>(offs, esrc, abuf);
  k_gemm1 <<<GGRID, 512, 0, stream>>>(abuf, wbf, partials);
  k_stats <<<1,    1024, 0, stream>>>(partials, bl, gamma, beta, ssbuf);
  k_norm  <<<6250,  256, 0, stream>>>(abuf, ssbuf, out);
}

// Round 16
// 154.370 us; speedup vs baseline: 1.0503x; 1.0007x over previous
//
#include <hip/hip_runtime.h>
#include <stdint.h>

#define NN 100000     // nodes
#define NE 640000     // edges
#define DD 128        // features
#define BN_EPS 1e-5f
#define NB 391        // scan blocks: 391*256 = 100096 >= NN
#define NROWPAD 100096
#define NTILE 782     // 128-row tiles: 782*128 = 100096
#define GGRID 512     // gemm grid (2 blocks/CU)

typedef __attribute__((ext_vector_type(8)))  short bf16x8;
typedef __attribute__((ext_vector_type(4)))  float f32x4;

static __device__ __forceinline__ float bf2f(unsigned short s) {
  return __uint_as_float(((unsigned)s) << 16);
}
static __device__ __forceinline__ unsigned short f2bf(float f) {
  unsigned u = __float_as_uint(f);
  u += 0x7FFFu + ((u >> 16) & 1u);   // RNE
  return (unsigned short)(u >> 16);
}

// ---- 0. zero deg ---------------------------------------------------------
__global__ __launch_bounds__(1024) void k_zero(int* __restrict__ deg)
{
  int i = blockIdx.x * 1024 + threadIdx.x;
  if (i < NROWPAD) deg[i] = 0;
}

// ---- 1. merged setup, INTERLEAVED roles ----------------------------------
// hist blocks (640K device-scope atomics) are every 4th block (b&3==3 ->
// exactly 2500), spread uniformly so atomics overlap the prep streaming
// from t=0 (worth ~8us vs sequential role ranges).
__global__ __launch_bounds__(256) void k_setup(
    const float* __restrict__ x,
    const float* __restrict__ Wl, const float* __restrict__ Wr,
    const int* __restrict__ ei,
    unsigned short* __restrict__ abuf, unsigned short* __restrict__ wbf,
    int* __restrict__ deg)
{
  int b = blockIdx.x;                   // grid 10000
  if ((b & 3) == 3) {
    int e = (b >> 2) * 256 + threadIdx.x;
    if (e < NE) atomicAdd(deg + ei[NE + e], 1);
    return;
  }
  int rank = b - (b >> 2);              // 0..7499
  if (rank < 6256) {
    // abuf[row][128+j] = bf16(relu(x[row][j])); pad rows zero BOTH halves
    int i = rank * 256 + threadIdx.x;   // 0 .. NROWPAD*16-1
    int row = i >> 4, cj = i & 15;
    if (row < NN) {
      const float* xp = x + (long)row * DD + cj * 8;
      float tmp[8];
      *(float4*)(tmp)     = *(const float4*)(xp);
      *(float4*)(tmp + 4) = *(const float4*)(xp + 4);
      bf16x8 o;
#pragma unroll
      for (int e = 0; e < 8; ++e) o[e] = (short)f2bf(fmaxf(tmp[e], 0.f));
      *(bf16x8*)(abuf + (long)row * 256 + DD + cj * 8) = o;
    } else {                            // rows NN..NROWPAD-1: zero fill
      bf16x8 z = {};
      *(bf16x8*)(abuf + (long)row * 256 + cj * 8) = z;        // agg half
      *(bf16x8*)(abuf + (long)row * 256 + DD + cj * 8) = z;   // x half
    }
  } else if (rank < 6384) {
    // wbf[col][0..255] = [Wl[col][:] | Wr[col][:]] as bf16
    int i = (rank - 6256) * 256 + threadIdx.x;
    int col = i >> 8, k = i & 255;
    float v = (k < DD) ? Wl[col * DD + k] : Wr[col * DD + (k - DD)];
    wbf[i] = f2bf(v);
  }
}

// ---- 2a. block sums ------------------------------------------------------
// SCAN MUST BE TWO LAUNCHES (R14/R15 crash lesson): a merged scan that
// strided-sums OTHER blocks' deg entries races with their deg[i]=cursor
// writes (dispatch order undefined) -> corrupt offs -> OOB esrc writes ->
// abort. bsum must be materialized by a completed launch first.
__global__ __launch_bounds__(256) void k_scan1(const int* __restrict__ deg,
                                               int* __restrict__ bsum)
{
  __shared__ int sc[256];
  int t = threadIdx.x;
  sc[t] = deg[blockIdx.x * 256 + t];
  __syncthreads();
  for (int s = 128; s > 0; s >>= 1) {
    if (t < s) sc[t] += sc[t + s];
    __syncthreads();
  }
  if (t == 0) bsum[blockIdx.x] = sc[0];
}

// ---- 2b. per-element exclusive scan (self-computes block prefix from
// STABLE bsum; reads/writes only its OWN deg block -> race-free) ----------
__global__ __launch_bounds__(256) void k_scan3(int* __restrict__ deg,
                                               const int* __restrict__ bsum,
                                               int* __restrict__ offs)
{
  __shared__ int sc[256];
  __shared__ int pre[256];
  int t = threadIdx.x;
  int p = 0;
  for (int j = t; j < blockIdx.x; j += 256) p += bsum[j];
  pre[t] = p;
  __syncthreads();
  for (int s = 128; s > 0; s >>= 1) {
    if (t < s) pre[t] += pre[t + s];
    __syncthreads();
  }
  int boff = pre[0];
  __syncthreads();
  int i = blockIdx.x * 256 + t;
  int v = deg[i];
  sc[t] = v;
  __syncthreads();
  for (int s = 1; s < 256; s <<= 1) {
    int add = (t >= s) ? sc[t - s] : 0;
    __syncthreads();
    sc[t] += add;
    __syncthreads();
  }
  int excl = sc[t] - v + boff;
  offs[i] = excl;
  deg[i]  = excl;     // deg becomes fill-cursor
}

// ---- 3. fill CSR ---------------------------------------------------------
__global__ __launch_bounds__(256) void k_fill(const int* __restrict__ ei,
                                              int* __restrict__ cursor,
                                              int* __restrict__ esrc)
{
  int e = blockIdx.x * 256 + threadIdx.x;
  if (e >= NE) return;
  int pos = atomicAdd(cursor + ei[NE + e], 1);
  esrc[pos] = ei[e];
}

// ---- 4. gather-aggregate: abuf[dst][0..127] = bf16(mean(relu_x_bf16[src]))
// R7/R10-proven 4x16 layout: 4 quarter-waves of 16 lanes own edge stream
// i*4+q; one wave-wide load covers 4 DIFFERENT edges' rows (4x MLP; 8x
// with unroll 2). R9's 8x8 variant went VALU-bound on the tripled reduce
// tail -- do not repeat. Lanes past the edge count hold src=NN (zeroed
// pad row) -> adds 0, branch-free.
__global__ __launch_bounds__(256) void k_agg(const int* __restrict__ offs,
                                             const int* __restrict__ esrc,
                                             unsigned short* __restrict__ abuf)
{
  int dst = blockIdx.x * 4 + (threadIdx.x >> 6);
  if (dst >= NN) return;
  int lane = threadIdx.x & 63;
  int q  = lane >> 4;        // quarter-wave 0..3 = edge slot
  int fl = lane & 15;        // feature lane: feats fl*8 .. fl*8+7
  int off = offs[dst], end = offs[dst + 1];
  int deg = end - off;
  float acc[8];
#pragma unroll
  for (int e = 0; e < 8; ++e) acc[e] = 0.f;

  for (int base = off; base < end; base += 64) {
    int m = end - base; if (m > 64) m = 64;
    int mysrc = (base + lane < end) ? esrc[base + lane] : NN;  // NN = zero pad row
    int iters = (m + 3) >> 2;
#pragma unroll 2
    for (int i = 0; i < iters; ++i) {
      int src = __shfl(mysrc, i * 4 + q);    // i*4+q <= 63; >=m lanes hold NN
      bf16x8 w = *(const bf16x8*)(abuf + (long)src * 256 + DD + fl * 8);
#pragma unroll
      for (int e = 0; e < 8; ++e) acc[e] += bf2f((unsigned short)w[e]);
    }
  }

#pragma unroll
  for (int e = 0; e < 8; ++e) {
    acc[e] += __shfl_xor(acc[e], 16);
    acc[e] += __shfl_xor(acc[e], 32);
  }
  if (q == 0) {
    float rinv = (deg > 0) ? 1.0f / (float)deg : 0.f;
    bf16x8 o;
#pragma unroll
    for (int e = 0; e < 8; ++e) o[e] = (short)f2bf(acc[e] * rinv);
    *(bf16x8*)(abuf + (long)dst * 256 + fl * 8) = o;
  }
}

// ======== streaming GEMM (single pass) ====================================
// Block: 512 thr = 8 waves. B (= wbf, 128x256 bf16 = 64KB) staged once in
// LDS with XOR-swizzle byte ^= (col&7)<<4. Each wave owns a 16-row strip
// per tile; A-fragments load DIRECTLY from global. No barriers in loop.
// REGISTER BUDGET: (512,2) caps VGPR at 128 (2 blocks/CU, LDS-bound); per-
// ks A-load unroll 4, <=4 frags in flight -> no spills.
// LDS BUDGET: blds is EXACTLY 64KB -- do not add __shared__ variables.
#define GEMM_STAGE_B() \
  _Pragma("unroll") \
  for (int j = 0; j < 8; ++j) { \
    int id = j * 512 + t, col = id >> 5, seg = id & 31; \
    uint4 v = *(const uint4*)(wbf + col * 256 + seg * 8); \
    int byte = (col << 9) + (seg << 4); byte ^= (col & 7) << 4; \
    *(uint4*)((char*)blds + byte) = v; \
  } \
  __syncthreads();

#define GEMM_TILE_COMPUTE(rb) \
  { const unsigned short* ap = abuf + (long)((rb) + c15) * 256 + kg * 8; \
    _Pragma("unroll 4") \
    for (int ks = 0; ks < 8; ++ks) { \
      bf16x8 a = *(const bf16x8*)(ap + ks * 32); \
      _Pragma("unroll") \
      for (int ct = 0; ct < 8; ++ct) { \
        int byte = ((ct * 16 + c15) << 9) + (ks << 6) + (kg << 4); \
        byte ^= (c15 & 7) << 4; \
        bf16x8 b = *(const bf16x8*)((const char*)blds + byte); \
        acc[ct] = __builtin_amdgcn_mfma_f32_16x16x32_bf16(a, b, acc[ct], 0, 0, 0); \
      } \
    } }

// ---- 5. GEMM: raw column stats + bf16 out_pre into abuf agg-half ---------
// Pad rows are zeroed in abuf -> contribute 0 to stats, store 0s.
__global__ __launch_bounds__(512, 2) void k_gemm1(
    unsigned short* __restrict__ abuf,
    const unsigned short* __restrict__ wbf,
    float* __restrict__ partials)
{
  __shared__ __align__(16) unsigned short blds[32768];   // 64KB B (FULL)
  const int t = threadIdx.x;
  const int lane = t & 63, wv = t >> 6;
  const int c15 = lane & 15, kg = lane >> 4;

  GEMM_STAGE_B();

  float sS[8], sQ[8];
#pragma unroll
  for (int ct = 0; ct < 8; ++ct) { sS[ct] = 0.f; sQ[ct] = 0.f; }

  for (int tile = blockIdx.x; tile < NTILE; tile += GGRID) {
    int rb = tile * 128 + wv * 16;
    f32x4 acc[8];
#pragma unroll
    for (int ct = 0; ct < 8; ++ct) acc[ct] = (f32x4){0.f, 0.f, 0.f, 0.f};
    GEMM_TILE_COMPUTE(rb);
#pragma unroll
    for (int ct = 0; ct < 8; ++ct) {
      int col = ct * 16 + c15;
#pragma unroll
      for (int r = 0; r < 4; ++r) {
        float v = acc[ct][r];
        sS[ct] += v;
        sQ[ct] += v * v;
        abuf[(long)(rb + kg * 4 + r) * 256 + col] = f2bf(v);  // out_pre bf16
      }
    }
  }

  // block-level reduce through LDS (B no longer needed)
  __syncthreads();
  float* slds = (float*)blds;   // [8 waves][256] = 8KB
#pragma unroll
  for (int ct = 0; ct < 8; ++ct) {
    float s = sS[ct], q = sQ[ct];
    s += __shfl_xor(s, 16); q += __shfl_xor(q, 16);
    s += __shfl_xor(s, 32); q += __shfl_xor(q, 32);
    if (lane < 16) {
      slds[wv * 256 + ct * 16 + lane] = s;
      slds[wv * 256 + 128 + ct * 16 + lane] = q;
    }
  }
  __syncthreads();
  if (t < 256) {
    float a = 0.f;
#pragma unroll
    for (int w = 0; w < 8; ++w) a += slds[w * 256 + t];
    partials[blockIdx.x * 256 + t] = a;
  }
}

// ---- 6. reduce partials; fold bias; emit sc / (bias*sc + shift) ----------
__global__ __launch_bounds__(1024) void k_stats(
    const float* __restrict__ partials, const float* __restrict__ bl,
    const float* __restrict__ gamma, const float* __restrict__ beta,
    float* __restrict__ ss)
{
  __shared__ float red[4][256];
  int t = threadIdx.x & 255, g = threadIdx.x >> 8;
  float a = 0.f;
#pragma unroll 8
  for (int blk = g; blk < GGRID; blk += 4) a += partials[blk * 256 + t];
  red[g][t] = a;
  __syncthreads();
  if (threadIdx.x < 256)
    red[0][t] = red[0][t] + red[1][t] + red[2][t] + red[3][t];
  __syncthreads();
  if (threadIdx.x < 128) {
    float Sr = red[0][t], Qr = red[0][128 + t];
    float b  = bl[t];
    float S  = Sr + (float)NN * b;                    // fold bias into stats
    float Q  = Qr + 2.f * b * Sr + (float)NN * b * b;
    float mu  = S / (float)NN;
    float var = Q / (float)NN - mu * mu;              // biased variance
    float rsig = rsqrtf(var + BN_EPS);
    float sc  = gamma[t] * rsig;
    float sh2 = beta[t] - mu * sc;
    ss[t]       = sc;
    ss[128 + t] = b * sc + sh2;                       // bias folded into shift
  }
}

// ---- 7. streaming BN affine: out = sc * out_pre(bf16) + shift ------------
__global__ __launch_bounds__(256) void k_norm(
    const unsigned short* __restrict__ abuf,
    const float* __restrict__ ss,
    float* __restrict__ out)
{
  __shared__ float sc[128], sh[128];
  if (threadIdx.x < 128) {
    sc[threadIdx.x] = ss[threadIdx.x];
    sh[threadIdx.x] = ss[128 + threadIdx.x];
  }
  __syncthreads();
  int i = blockIdx.x * 256 + threadIdx.x;   // 0 .. NN*16-1
  int row = i >> 4, cj = i & 15;
  if (row >= NN) return;
  bf16x8 v = *(const bf16x8*)(abuf + (long)row * 256 + cj * 8);
  int c0 = cj * 8;
  float4 o0, o1;
  o0.x = fmaf(bf2f((unsigned short)v[0]), sc[c0 + 0], sh[c0 + 0]);
  o0.y = fmaf(bf2f((unsigned short)v[1]), sc[c0 + 1], sh[c0 + 1]);
  o0.z = fmaf(bf2f((unsigned short)v[2]), sc[c0 + 2], sh[c0 + 2]);
  o0.w = fmaf(bf2f((unsigned short)v[3]), sc[c0 + 3], sh[c0 + 3]);
  o1.x = fmaf(bf2f((unsigned short)v[4]), sc[c0 + 4], sh[c0 + 4]);
  o1.y = fmaf(bf2f((unsigned short)v[5]), sc[c0 + 5], sh[c0 + 5]);
  o1.z = fmaf(bf2f((unsigned short)v[6]), sc[c0 + 6], sh[c0 + 6]);
  o1.w = fmaf(bf2f((unsigned short)v[7]), sc[c0 + 7], sh[c0 + 7]);
  *(float4*)(out + (long)row * DD + c0)     = o0;
  *(float4*)(out + (long)row * DD + c0 + 4) = o1;
}

extern "C" void kernel_launch(void* const* d_in, const int* in_sizes, int n_in,
                              void* d_out, int out_size, void* d_ws, size_t ws_size,
                              hipStream_t stream)
{
  const float* x     = (const float*)d_in[0];
  // d_in[1] = edge_attr — unused by the reference
  const float* Wl    = (const float*)d_in[2];
  const float* bl    = (const float*)d_in[3];
  const float* Wr    = (const float*)d_in[4];
  const float* gamma = (const float*)d_in[5];
  const float* beta  = (const float*)d_in[6];
  const int*   ei    = (const int*)d_in[7];
  float* out = (float*)d_out;

  char* ws = (char*)d_ws;
  unsigned short* abuf = (unsigned short*)(ws);            // 100096*256*2 = 51,249,152
  int*   esrc  = (int*)(ws + 51249152);                    //  2,560,000 -> 53,809,152
  int*   deg   = (int*)(ws + 53809152);                    //    400,384 -> 54,209,536
  int*   offs  = (int*)(ws + 54209536);                    //    400,384 -> 54,609,920
  int*   bsum  = (int*)(ws + 54609920);                    //      2,048 -> 54,611,968
  unsigned short* wbf = (unsigned short*)(ws + 54611968);  //     65,536 -> 54,677,504
  // dead-region reuse (stream-ordered):
  float* partials = (float*)esrc;   // gemm1 partials [512][256] f32; esrc dead after k_agg
  float* ssbuf    = (float*)deg;    // 256 f32; deg dead (as cursor) after k_fill
  (void)ws_size; (void)in_sizes; (void)n_in; (void)out_size;

  k_zero  <<<98,   1024, 0, stream>>>(deg);
  k_setup <<<10000, 256, 0, stream>>>(x, Wl, Wr, ei, abuf, wbf, deg);
  k_scan1 <<<NB,    256, 0, stream>>>(deg, bsum);
  k_scan3 <<<NB,    256, 0, stream>>>(deg, bsum, offs);
  k_fill  <<<2500,  256, 0, stream>>>(ei, deg, esrc);
  k_agg   <<<25000, 256, 0, stream>>>(offs, esrc, abuf);
  k_gemm1 <<<GGRID, 512, 0, stream>>>(abuf, wbf, partials);
  k_stats <<<1,    1024, 0, stream>>>(partials, bl, gamma, beta, ssbuf);
  k_norm  <<<6250,  256, 0, stream>>>(abuf, ssbuf, out);
}

// Round 17
// 152.152 us; speedup vs baseline: 1.0656x; 1.0146x over previous
//
#include <hip/hip_runtime.h>
#include <stdint.h>

#define NN 100000     // nodes
#define NE 640000     // edges
#define DD 128        // features
#define BN_EPS 1e-5f
#define NB 391        // scan blocks: 391*256 = 100096 >= NN
#define NROWPAD 100096
#define NTILE 782     // 128-row tiles: 782*128 = 100096
#define GGRID 512     // gemm grid (2 blocks/CU)

typedef __attribute__((ext_vector_type(8)))  short bf16x8;
typedef __attribute__((ext_vector_type(4)))  float f32x4;

static __device__ __forceinline__ float bf2f(unsigned short s) {
  return __uint_as_float(((unsigned)s) << 16);
}
static __device__ __forceinline__ unsigned short f2bf(float f) {
  unsigned u = __float_as_uint(f);
  u += 0x7FFFu + ((u >> 16) & 1u);   // RNE
  return (unsigned short)(u >> 16);
}

// R16 LAYOUT: abuf split into two COMPACT buffers.
//   xbf [NROWPAD][128] bf16 : relu(x), the k_agg gather source. Compact
//       256B rows -> every fetched cache line is 100% gather data (the old
//       512B-stride interleave made k_agg fetch 74.6MB for 25.6MB unique).
//   magg[NROWPAD][128] bf16 : mean-agg; after gemm reads it as A it is
//       overwritten in-place with out_pre (each gemm block writes only the
//       rows it alone reads -> no hazard).

// ---- 0. zero deg ---------------------------------------------------------
__global__ __launch_bounds__(1024) void k_zero(int* __restrict__ deg)
{
  int i = blockIdx.x * 1024 + threadIdx.x;
  if (i < NROWPAD) deg[i] = 0;
}

// ---- 1. merged setup, INTERLEAVED roles ----------------------------------
// hist blocks (640K device-scope atomics) are every 4th block (b&3==3 ->
// exactly 2500), spread uniformly so atomics overlap the prep streaming
// from t=0 (worth ~8us vs sequential role ranges).
__global__ __launch_bounds__(256) void k_setup(
    const float* __restrict__ x,
    const float* __restrict__ Wl, const float* __restrict__ Wr,
    const int* __restrict__ ei,
    unsigned short* __restrict__ xbf, unsigned short* __restrict__ magg,
    unsigned short* __restrict__ wbf, int* __restrict__ deg)
{
  int b = blockIdx.x;                   // grid 10000
  if ((b & 3) == 3) {
    int e = (b >> 2) * 256 + threadIdx.x;
    if (e < NE) atomicAdd(deg + ei[NE + e], 1);
    return;
  }
  int rank = b - (b >> 2);              // 0..7499
  if (rank < 6256) {
    // xbf[row][j] = bf16(relu(x[row][j])); pad rows zero xbf AND magg
    int i = rank * 256 + threadIdx.x;   // 0 .. NROWPAD*16-1
    int row = i >> 4, cj = i & 15;
    if (row < NN) {
      const float* xp = x + (long)row * DD + cj * 8;
      float tmp[8];
      *(float4*)(tmp)     = *(const float4*)(xp);
      *(float4*)(tmp + 4) = *(const float4*)(xp + 4);
      bf16x8 o;
#pragma unroll
      for (int e = 0; e < 8; ++e) o[e] = (short)f2bf(fmaxf(tmp[e], 0.f));
      *(bf16x8*)(xbf + (long)row * DD + cj * 8) = o;
    } else {                            // rows NN..NROWPAD-1: zero fill
      bf16x8 z = {};
      *(bf16x8*)(xbf  + (long)row * DD + cj * 8) = z;
      *(bf16x8*)(magg + (long)row * DD + cj * 8) = z;
    }
  } else if (rank < 6384) {
    // wbf[col][0..255] = [Wl[col][:] | Wr[col][:]] as bf16
    int i = (rank - 6256) * 256 + threadIdx.x;
    int col = i >> 8, k = i & 255;
    float v = (k < DD) ? Wl[col * DD + k] : Wr[col * DD + (k - DD)];
    wbf[i] = f2bf(v);
  }
}

// ---- 2a. block sums ------------------------------------------------------
// SCAN MUST BE TWO LAUNCHES (R14/R15 crash lesson): a merged scan that
// strided-sums OTHER blocks' deg entries races with their deg[i]=cursor
// writes (dispatch order undefined) -> corrupt offs -> OOB esrc writes ->
// abort. bsum must be materialized by a completed launch first.
__global__ __launch_bounds__(256) void k_scan1(const int* __restrict__ deg,
                                               int* __restrict__ bsum)
{
  __shared__ int sc[256];
  int t = threadIdx.x;
  sc[t] = deg[blockIdx.x * 256 + t];
  __syncthreads();
  for (int s = 128; s > 0; s >>= 1) {
    if (t < s) sc[t] += sc[t + s];
    __syncthreads();
  }
  if (t == 0) bsum[blockIdx.x] = sc[0];
}

// ---- 2b. per-element exclusive scan (self-computes block prefix from
// STABLE bsum; reads/writes only its OWN deg block -> race-free) ----------
__global__ __launch_bounds__(256) void k_scan3(int* __restrict__ deg,
                                               const int* __restrict__ bsum,
                                               int* __restrict__ offs)
{
  __shared__ int sc[256];
  __shared__ int pre[256];
  int t = threadIdx.x;
  int p = 0;
  for (int j = t; j < blockIdx.x; j += 256) p += bsum[j];
  pre[t] = p;
  __syncthreads();
  for (int s = 128; s > 0; s >>= 1) {
    if (t < s) pre[t] += pre[t + s];
    __syncthreads();
  }
  int boff = pre[0];
  __syncthreads();
  int i = blockIdx.x * 256 + t;
  int v = deg[i];
  sc[t] = v;
  __syncthreads();
  for (int s = 1; s < 256; s <<= 1) {
    int add = (t >= s) ? sc[t - s] : 0;
    __syncthreads();
    sc[t] += add;
    __syncthreads();
  }
  int excl = sc[t] - v + boff;
  offs[i] = excl;
  deg[i]  = excl;     // deg becomes fill-cursor
}

// ---- 3. fill CSR ---------------------------------------------------------
__global__ __launch_bounds__(256) void k_fill(const int* __restrict__ ei,
                                              int* __restrict__ cursor,
                                              int* __restrict__ esrc)
{
  int e = blockIdx.x * 256 + threadIdx.x;
  if (e >= NE) return;
  int pos = atomicAdd(cursor + ei[NE + e], 1);
  esrc[pos] = ei[e];
}

// ---- 4. gather-aggregate: magg[dst] = bf16(mean(xbf[src])) ---------------
// R7/R10-proven 4x16 layout: 4 quarter-waves of 16 lanes own edge stream
// i*4+q; one wave-wide load covers 4 DIFFERENT edges' compact 256B rows
// (4x MLP; 8x with unroll 2). R9's 8x8 variant went VALU-bound on the
// tripled reduce tail -- do not repeat. Lanes past the edge count hold
// src=NN (zeroed pad row) -> adds 0, branch-free.
__global__ __launch_bounds__(256) void k_agg(const int* __restrict__ offs,
                                             const int* __restrict__ esrc,
                                             const unsigned short* __restrict__ xbf,
                                             unsigned short* __restrict__ magg)
{
  int dst = blockIdx.x * 4 + (threadIdx.x >> 6);
  if (dst >= NN) return;
  int lane = threadIdx.x & 63;
  int q  = lane >> 4;        // quarter-wave 0..3 = edge slot
  int fl = lane & 15;        // feature lane: feats fl*8 .. fl*8+7
  int off = offs[dst], end = offs[dst + 1];
  int deg = end - off;
  float acc[8];
#pragma unroll
  for (int e = 0; e < 8; ++e) acc[e] = 0.f;

  for (int base = off; base < end; base += 64) {
    int m = end - base; if (m > 64) m = 64;
    int mysrc = (base + lane < end) ? esrc[base + lane] : NN;  // NN = zero pad row
    int iters = (m + 3) >> 2;
#pragma unroll 2
    for (int i = 0; i < iters; ++i) {
      int src = __shfl(mysrc, i * 4 + q);    // i*4+q <= 63; >=m lanes hold NN
      bf16x8 w = *(const bf16x8*)(xbf + (long)src * DD + fl * 8);
#pragma unroll
      for (int e = 0; e < 8; ++e) acc[e] += bf2f((unsigned short)w[e]);
    }
  }

#pragma unroll
  for (int e = 0; e < 8; ++e) {
    acc[e] += __shfl_xor(acc[e], 16);
    acc[e] += __shfl_xor(acc[e], 32);
  }
  if (q == 0) {
    float rinv = (deg > 0) ? 1.0f / (float)deg : 0.f;
    bf16x8 o;
#pragma unroll
    for (int e = 0; e < 8; ++e) o[e] = (short)f2bf(acc[e] * rinv);
    *(bf16x8*)(magg + (long)dst * DD + fl * 8) = o;
  }
}

// ======== streaming GEMM (single pass) ====================================
// Block: 512 thr = 8 waves. B (= wbf, 128x256 bf16 = 64KB) staged once in
// LDS with XOR-swizzle byte ^= (col&7)<<4. Each wave owns a 16-row strip
// per tile; A-fragments load DIRECTLY from global: K 0..127 from magg row,
// K 128..255 from xbf row (two compact base pointers). No barriers in loop.
// REGISTER BUDGET: (512,2) caps VGPR at 128 (2 blocks/CU, LDS-bound); per-
// ks A-load unroll 4, <=4 frags in flight -> no spills.
// LDS BUDGET: blds is EXACTLY 64KB -- do not add __shared__ variables.
#define GEMM_STAGE_B() \
  _Pragma("unroll") \
  for (int j = 0; j < 8; ++j) { \
    int id = j * 512 + t, col = id >> 5, seg = id & 31; \
    uint4 v = *(const uint4*)(wbf + col * 256 + seg * 8); \
    int byte = (col << 9) + (seg << 4); byte ^= (col & 7) << 4; \
    *(uint4*)((char*)blds + byte) = v; \
  } \
  __syncthreads();

#define GEMM_TILE_COMPUTE(rb) \
  { const unsigned short* ap0 = magg + (long)((rb) + c15) * DD + kg * 8; \
    const unsigned short* ap1 = xbf  + (long)((rb) + c15) * DD + kg * 8; \
    _Pragma("unroll 4") \
    for (int ks = 0; ks < 8; ++ks) { \
      bf16x8 a = (ks < 4) ? *(const bf16x8*)(ap0 + ks * 32) \
                          : *(const bf16x8*)(ap1 + (ks - 4) * 32); \
      _Pragma("unroll") \
      for (int ct = 0; ct < 8; ++ct) { \
        int byte = ((ct * 16 + c15) << 9) + (ks << 6) + (kg << 4); \
        byte ^= (c15 & 7) << 4; \
        bf16x8 b = *(const bf16x8*)((const char*)blds + byte); \
        acc[ct] = __builtin_amdgcn_mfma_f32_16x16x32_bf16(a, b, acc[ct], 0, 0, 0); \
      } \
    } }

// ---- 5. GEMM: raw column stats + bf16 out_pre OVER magg ------------------
// Pad rows are zeroed in xbf+magg -> contribute 0 to stats, store 0s.
__global__ __launch_bounds__(512, 2) void k_gemm1(
    unsigned short* __restrict__ magg,
    const unsigned short* __restrict__ xbf,
    const unsigned short* __restrict__ wbf,
    float* __restrict__ partials)
{
  __shared__ __align__(16) unsigned short blds[32768];   // 64KB B (FULL)
  const int t = threadIdx.x;
  const int lane = t & 63, wv = t >> 6;
  const int c15 = lane & 15, kg = lane >> 4;

  GEMM_STAGE_B();

  float sS[8], sQ[8];
#pragma unroll
  for (int ct = 0; ct < 8; ++ct) { sS[ct] = 0.f; sQ[ct] = 0.f; }

  for (int tile = blockIdx.x; tile < NTILE; tile += GGRID) {
    int rb = tile * 128 + wv * 16;
    f32x4 acc[8];
#pragma unroll
    for (int ct = 0; ct < 8; ++ct) acc[ct] = (f32x4){0.f, 0.f, 0.f, 0.f};
    GEMM_TILE_COMPUTE(rb);
#pragma unroll
    for (int ct = 0; ct < 8; ++ct) {
      int col = ct * 16 + c15;
#pragma unroll
      for (int r = 0; r < 4; ++r) {
        float v = acc[ct][r];
        sS[ct] += v;
        sQ[ct] += v * v;
        magg[(long)(rb + kg * 4 + r) * DD + col] = f2bf(v);  // out_pre bf16
      }
    }
  }

  // block-level reduce through LDS (B no longer needed)
  __syncthreads();
  float* slds = (float*)blds;   // [8 waves][256] = 8KB
#pragma unroll
  for (int ct = 0; ct < 8; ++ct) {
    float s = sS[ct], q = sQ[ct];
    s += __shfl_xor(s, 16); q += __shfl_xor(q, 16);
    s += __shfl_xor(s, 32); q += __shfl_xor(q, 32);
    if (lane < 16) {
      slds[wv * 256 + ct * 16 + lane] = s;
      slds[wv * 256 + 128 + ct * 16 + lane] = q;
    }
  }
  __syncthreads();
  if (t < 256) {
    float a = 0.f;
#pragma unroll
    for (int w = 0; w < 8; ++w) a += slds[w * 256 + t];
    partials[blockIdx.x * 256 + t] = a;
  }
}

// ---- 6. reduce partials; fold bias; emit sc / (bias*sc + shift) ----------
__global__ __launch_bounds__(1024) void k_stats(
    const float* __restrict__ partials, const float* __restrict__ bl,
    const float* __restrict__ gamma, const float* __restrict__ beta,
    float* __restrict__ ss)
{
  __shared__ float red[4][256];
  int t = threadIdx.x & 255, g = threadIdx.x >> 8;
  float a = 0.f;
#pragma unroll 8
  for (int blk = g; blk < GGRID; blk += 4) a += partials[blk * 256 + t];
  red[g][t] = a;
  __syncthreads();
  if (threadIdx.x < 256)
    red[0][t] = red[0][t] + red[1][t] + red[2][t] + red[3][t];
  __syncthreads();
  if (threadIdx.x < 128) {
    float Sr = red[0][t], Qr = red[0][128 + t];
    float b  = bl[t];
    float S  = Sr + (float)NN * b;                    // fold bias into stats
    float Q  = Qr + 2.f * b * Sr + (float)NN * b * b;
    float mu  = S / (float)NN;
    float var = Q / (float)NN - mu * mu;              // biased variance
    float rsig = rsqrtf(var + BN_EPS);
    float sc  = gamma[t] * rsig;
    float sh2 = beta[t] - mu * sc;
    ss[t]       = sc;
    ss[128 + t] = b * sc + sh2;                       // bias folded into shift
  }
}

// ---- 7. streaming BN affine: out = sc * out_pre(bf16) + shift ------------
// R16: grid geometry MATCHES k_gemm1 (512 blocks, tile = bid + 512-stride)
// so block b re-reads the out_pre rows gemm block b wrote -- with the
// empirical blockIdx%8 XCD mapping these reads hit the same XCD's L2.
// Heuristic only: affects speed, never correctness.
__global__ __launch_bounds__(512) void k_norm(
    const unsigned short* __restrict__ magg,
    const float* __restrict__ ss,
    float* __restrict__ out)
{
  __shared__ float sc[128], sh[128];
  if (threadIdx.x < 128) {
    sc[threadIdx.x] = ss[threadIdx.x];
    sh[threadIdx.x] = ss[128 + threadIdx.x];
  }
  __syncthreads();
  for (int tile = blockIdx.x; tile < NTILE; tile += GGRID) {
    long tb = (long)tile * 128;
    for (int i = threadIdx.x; i < 2048; i += 512) {   // 128 rows x 16 chunks
      long row = tb + (i >> 4);
      if (row >= NN) continue;
      int c0 = (i & 15) * 8;
      bf16x8 v = *(const bf16x8*)(magg + row * DD + c0);
      float4 o0, o1;
      o0.x = fmaf(bf2f((unsigned short)v[0]), sc[c0 + 0], sh[c0 + 0]);
      o0.y = fmaf(bf2f((unsigned short)v[1]), sc[c0 + 1], sh[c0 + 1]);
      o0.z = fmaf(bf2f((unsigned short)v[2]), sc[c0 + 2], sh[c0 + 2]);
      o0.w = fmaf(bf2f((unsigned short)v[3]), sc[c0 + 3], sh[c0 + 3]);
      o1.x = fmaf(bf2f((unsigned short)v[4]), sc[c0 + 4], sh[c0 + 4]);
      o1.y = fmaf(bf2f((unsigned short)v[5]), sc[c0 + 5], sh[c0 + 5]);
      o1.z = fmaf(bf2f((unsigned short)v[6]), sc[c0 + 6], sh[c0 + 6]);
      o1.w = fmaf(bf2f((unsigned short)v[7]), sc[c0 + 7], sh[c0 + 7]);
      *(float4*)(out + row * DD + c0)     = o0;
      *(float4*)(out + row * DD + c0 + 4) = o1;
    }
  }
}

extern "C" void kernel_launch(void* const* d_in, const int* in_sizes, int n_in,
                              void* d_out, int out_size, void* d_ws, size_t ws_size,
                              hipStream_t stream)
{
  const float* x     = (const float*)d_in[0];
  // d_in[1] = edge_attr — unused by the reference
  const float* Wl    = (const float*)d_in[2];
  const float* bl    = (const float*)d_in[3];
  const float* Wr    = (const float*)d_in[4];
  const float* gamma = (const float*)d_in[5];
  const float* beta  = (const float*)d_in[6];
  const int*   ei    = (const int*)d_in[7];
  float* out = (float*)d_out;

  char* ws = (char*)d_ws;
  unsigned short* magg = (unsigned short*)(ws);            // 100096*128*2 = 25,624,576
  unsigned short* xbf  = (unsigned short*)(ws + 25624576); // 25,624,576 -> 51,249,152
  int*   esrc  = (int*)(ws + 51249152);                    //  2,560,000 -> 53,809,152
  int*   deg   = (int*)(ws + 53809152);                    //    400,384 -> 54,209,536
  int*   offs  = (int*)(ws + 54209536);                    //    400,384 -> 54,609,920
  int*   bsum  = (int*)(ws + 54609920);                    //      2,048 -> 54,611,968
  unsigned short* wbf = (unsigned short*)(ws + 54611968);  //     65,536 -> 54,677,504
  // dead-region reuse (stream-ordered):
  float* partials = (float*)esrc;   // gemm1 partials [512][256] f32; esrc dead after k_agg
  float* ssbuf    = (float*)deg;    // 256 f32; deg dead (as cursor) after k_fill
  (void)ws_size; (void)in_sizes; (void)n_in; (void)out_size;

  k_zero  <<<98,   1024, 0, stream>>>(deg);
  k_setup <<<10000, 256, 0, stream>>>(x, Wl, Wr, ei, xbf, magg, wbf, deg);
  k_scan1 <<<NB,    256, 0, stream>>>(deg, bsum);
  k_scan3 <<<NB,    256, 0, stream>>>(deg, bsum, offs);
  k_fill  <<<2500,  256, 0, stream>>>(ei, deg, esrc);
  k_agg   <<<25000, 256, 0, stream>>>(offs, esrc, xbf, magg);
  k_gemm1 <<<GGRID, 512, 0, stream>>>(magg, xbf, wbf, partials);
  k_stats <<<1,    1024, 0, stream>>>(partials, bl, gamma, beta, ssbuf);
  k_norm  <<<GGRID, 512, 0, stream>>>(magg, ssbuf, out);
}